// Round 1
// baseline (627.917 us; speedup 1.0000x reference)
//
#include <hip/hip_runtime.h>

// Problem constants (from reference setup)
constexpr int N_ = 2, Z_ = 40, Y_ = 400, X_ = 400;
constexpr int G_ = 30000;     // grid query positions
constexpr int M_ = 120000;    // feature rows
constexpr int C_ = 64;        // channels
constexpr int K_ = 64;        // neighborhood size (p=4 -> 4^3)

// LDS feature tile stored transposed: s_feat[c * 65 + k].
// 65 ≡ 1 (mod 32)  =>  phase-2 writes and phase-3 reads are <=2-way
// bank-aliased (2-way is free on CDNA4, learn_hip m136).
constexpr int LSTR = C_ + 1;   // 65

// Output layout (flat, in return order):
//   sampled_features: [C, G, K]  = C_*G_*K_ floats
//   gpf:              [4, G, K]  = 4*G_*K_ floats
//   empty_mask:       [G]        = G_ floats (bool -> 0.0/1.0)

__global__ __launch_bounds__(256) void grouper_kernel(
    const int*   __restrict__ voxel_maps,     // [N,Z,Y,X]
    const int*   __restrict__ grid_positions, // [G,4]
    const float* __restrict__ features,       // [M,C]
    const int*   __restrict__ index_offset,   // [1,K,4]
    float*       __restrict__ out)
{
    __shared__ int   s_idx[K_];
    __shared__ float s_feat[C_ * LSTR];       // 16.6 KB, transposed [c][k]

    const int g = blockIdx.x;                 // one grid position per block
    const int t = threadIdx.x;                // 256 threads

    const long long GK = (long long)G_ * K_;
    float* out_sf   = out;                              // [C,G,K]
    float* out_gpf  = out + (long long)C_ * GK;         // [4,G,K]
    float* out_mask = out + (long long)(C_ + 4) * GK;   // [G]

    // ---------------- phase 1 ----------------
    // wave 0: voxel lookup for all K, publish sidx, emit mask
    // wave 1: gpf planes (depend only on index_offset) — overlaps wave 0's gather
    if (t < K_) {
        const int k = t;
        const int4 off = ((const int4*)index_offset)[k];
        const int4 gp  = ((const int4*)grid_positions)[g];   // wave-uniform

        const int n = gp.x + off.x;                          // off.x == 0 (no clip in ref)
        const int z = min(max(gp.y + off.y, 0), Z_ - 1);
        const int y = min(max(gp.z + off.z, 0), Y_ - 1);
        const int x = min(max(gp.w + off.w, 0), X_ - 1);

        const int sidx = voxel_maps[((n * Z_ + z) * Y_ + y) * X_ + x];
        s_idx[k] = sidx;

        // empty mask: sum_k (sidx+1) == 0  <=>  all sidx == -1 (terms >= 0)
        const bool all_empty = __all(sidx == -1);
        if (k == 0) out_mask[g] = all_empty ? 1.0f : 0.0f;
    } else if (t < 2 * K_) {
        const int k = t - K_;
        const int4 off = ((const int4*)index_offset)[k];
        const long long gk = (long long)g * K_ + k;
        // integer positions contribute 0 after (x - floor(x)); only raw offsets remain
        out_gpf[0 * GK + gk] = (float)off.x;
        out_gpf[1 * GK + gk] = (float)off.y;
        out_gpf[2 * GK + gk] = (float)off.z;
        out_gpf[3 * GK + gk] = (float)off.w;
    }
    __syncthreads();

    // ---------------- phase 2 ----------------
    // Cooperative row gather -> LDS transpose.
    // Pass p: 16 threads per row, each reads one float4 (16 B) of the 256 B row.
    // Per wave-instruction: 4 dense 256 B segments (vs 64 scattered 16 B before).
    {
        const int q  = t & 15;        // float4 column within row
        const int kr = t >> 4;        // 0..15 row within pass
        #pragma unroll
        for (int p = 0; p < 4; ++p) {
            const int k    = p * 16 + kr;
            const int sidx = s_idx[k];
            float4 v = make_float4(0.f, 0.f, 0.f, 0.f);
            if (sidx >= 0)
                v = ((const float4*)(features + (long long)sidx * C_))[q];
            const int c0 = q * 4;
            s_feat[(c0 + 0) * LSTR + k] = v.x;
            s_feat[(c0 + 1) * LSTR + k] = v.y;
            s_feat[(c0 + 2) * LSTR + k] = v.z;
            s_feat[(c0 + 3) * LSTR + k] = v.w;
        }
    }
    __syncthreads();

    // ---------------- phase 3 ----------------
    // Coalesced float4 stores: pass p writes channels p*16 + (t>>4);
    // 16 threads cover k=0..63 with one float4 each -> dense 256 B per (c,g).
    {
        const int kq = (t & 15) * 4;  // k quad start
        const int cr = t >> 4;        // 0..15
        const long long base = (long long)g * K_;
        #pragma unroll
        for (int p = 0; p < 4; ++p) {
            const int c = p * 16 + cr;
            float4 v;
            v.x = s_feat[c * LSTR + kq + 0];
            v.y = s_feat[c * LSTR + kq + 1];
            v.z = s_feat[c * LSTR + kq + 2];
            v.w = s_feat[c * LSTR + kq + 3];
            *(float4*)(out_sf + (long long)c * GK + base + kq) = v;
        }
    }
}

extern "C" void kernel_launch(void* const* d_in, const int* in_sizes, int n_in,
                              void* d_out, int out_size, void* d_ws, size_t ws_size,
                              hipStream_t stream) {
    const int*   voxel_maps     = (const int*)d_in[0];
    const int*   grid_positions = (const int*)d_in[1];
    const float* features       = (const float*)d_in[2];
    const int*   index_offset   = (const int*)d_in[3];
    float*       out            = (float*)d_out;

    grouper_kernel<<<G_, 256, 0, stream>>>(
        voxel_maps, grid_positions, features, index_offset, out);
}